// Round 10
// baseline (304.408 us; speedup 1.0000x reference)
//
#include <hip/hip_runtime.h>

// Performer (FAVOR+) self-attention. B=4 H=8 N=8192 D=64 M=256.
// Round 20 = r19 + kCtx 3-blocks/CU:
//  - kCtx LDS 73.5 -> 51 KB: BxH deleted (proj B-frags read from global BxG,
//    L2-resident; asm pointer-opaque per chunk to block loop-invariant
//    hoisting into 64 regs = the r18 failure mode), epilogue scratch
//    (ksred/vred/wmax) overlaid into VF (dead after final p2 barrier).
//  - launch_bounds(512,6): 3 blocks/CU = 24 waves (was 16). VGPR cap 85;
//    live-state ~84. Tripwire: WRITE_SIZE >> 24 MB = spill -> revert.
// kOut unchanged from r19 (Q prefetch + Ff stride 260).
// kPrep -> kCtx -> kRedCtx -> kOut

typedef __attribute__((ext_vector_type(8))) short short8;
typedef __attribute__((ext_vector_type(8))) _Float16 half8;
typedef __attribute__((ext_vector_type(4))) float f32x4;

namespace {
constexpr int BN = 8192, DD = 64, MM = 256, NHEADS = 32;
constexpr float CNORM = 0.35355339059327373f;   // D^-0.25
constexpr float LOG2E = 1.4426950408889634f;
constexpr float DGC   = 0.34657359027997264f;   // 0.5/LOG2E
constexpr float FEPS  = 1e-4f;
constexpr float INV2048 = 4.8828125e-4f;
constexpr int FFS = 260;                        // kOut Ff stride (ushorts)

// workspace layout in floats (total 4,555,008 f = 18.22 MB, unchanged)
constexpr size_t OFF_BX    = 0;         // 16384 ushort = 8192 f
constexpr size_t OFF_CS    = 8192;      // 32*16384 ushort -> ends 270336
constexpr size_t OFF_KSUMP = 270336;    // 32*16*128 = 65536 -> 335872
constexpr size_t OFF_KSUMG = 335872;    // 32*256 = 8192 -> 344064 (mx packed @ +240..255/bh)
constexpr size_t OFF_VSP   = 344320;    // 32*8*64 = 16384 -> 360704
constexpr size_t OFF_CTXP  = 360704;    // 32*16*8192 = 4194304 -> 4555008
}

__device__ __forceinline__ unsigned short f2bf(float f) {
  unsigned u = __float_as_uint(f);
  u += 0x7fffu + ((u >> 16) & 1u);
  return (unsigned short)(u >> 16);
}
__device__ __forceinline__ float bf2f(unsigned short h) {
  return __uint_as_float(((unsigned)h) << 16);
}
__device__ __forceinline__ unsigned pk2(unsigned short a, unsigned short b) {
  return (unsigned)a | ((unsigned)b << 16);
}
__device__ __forceinline__ unsigned short f2h(float f) {
  _Float16 h = (_Float16)f;
  return __builtin_bit_cast(unsigned short, h);
}
__device__ __forceinline__ float exp2hw(float x) {
  float r;
  asm("v_exp_f32 %0, %1" : "=v"(r) : "v"(x));
  return r;
}
__device__ __forceinline__ unsigned cvtpk(float lo, float hi) {
  unsigned r;
  asm("v_cvt_pk_bf16_f32 %0, %1, %2" : "=v"(r) : "v"(lo), "v"(hi));
  return r;
}

// XCD swizzle: linear id -> (bh, tile); each XCD owns 4 consecutive heads.
template <int T>
__device__ __forceinline__ void xcd_map(int& bh, int& tile) {
  int id = blockIdx.y * T + blockIdx.x;
  int xcd = id & 7, s = id >> 3;
  bh = xcd * 4 + s / T;
  tile = s % T;
}

// ---------------- kPrep: proj -> single-f16 frag stream (32 KB) ----------------
// BxG[mt 16][kb 2][lane 64][8 f16]; kb = K-half (d 0-31 / 32-63).
__global__ void kPrep(const float* __restrict__ proj, unsigned short* __restrict__ BxG) {
  int s = blockIdx.x * 256 + threadIdx.x;   // 0..2047
  int l = s & 63, kb = (s >> 6) & 1, mt = s >> 7;
  int n = mt * 16 + (l & 15);
  int k0 = kb * 32 + (l >> 4) * 8;
  unsigned short o[8];
#pragma unroll
  for (int j = 0; j < 8; ++j) o[j] = f2h(proj[n * 64 + k0 + j]);
  *(uint4*)(BxG + (size_t)s * 8) =
      make_uint4(pk2(o[0], o[1]), pk2(o[2], o[3]), pk2(o[4], o[5]), pk2(o[6], o[7]));
}

// ---------------- kCtx: unscaled k-feature pipeline -> ctx/ksum partials + max ----------------
// Block = (bh, tile, mh): 1024 rows (8 chunks x 128), m-half mh*128..+128.
// LDS 51 KB -> 3 blocks/CU. B-frags from global BxG (L2); epilogue scratch
// aliased into VF.
__global__ void __launch_bounds__(512, 6)
kCtx(const float* __restrict__ Kin, const float* __restrict__ Vin,
     const float* __restrict__ mask, const unsigned short* __restrict__ BxG,
     float* __restrict__ ctxp, float* __restrict__ ksump,
     float* __restrict__ mxg, float* __restrict__ vsp) {
  __shared__ __align__(16) unsigned short Fs[128 * 140];  // 35 KB features [m][n]
  __shared__ __align__(16) unsigned short VF[16 * 64 * 8];// 16 KB; epilogue scratch aliases
  float* ksred = (float*)VF;             // 1024 f (epilogue only)
  float* vred  = (float*)VF + 1024;      // 512 f  (epilogue only)
  float* wmax  = (float*)VF + 1536;      // 8 f    (epilogue only)
  const int tid = threadIdx.x;
  int bh, tl16;
  xcd_map<16>(bh, tl16);
  const int tile = tl16 >> 1, mh = tl16 & 1;
  const int b = bh >> 3;
  const float* Kh = Kin + (size_t)bh * BN * DD;
  const float* Vh = Vin + (size_t)bh * BN * DD;
  const float* mrow = mask + (size_t)b * BN;
  const int w = tid >> 6, l = tid & 63, lm = l & 15, kl = l >> 4;
  const int lmv = tid & 15, klnv = (tid >> 4) & 3, dtv = (tid >> 6) & 3, ksv0 = tid >> 8;

  f32x4 cacc[4];
#pragma unroll
  for (int dt = 0; dt < 4; ++dt) cacc[dt] = f32x4{0.f, 0.f, 0.f, 0.f};
  float kspart[8] = {0.f, 0.f, 0.f, 0.f, 0.f, 0.f, 0.f, 0.f};
  float wm = -3e38f, vsum = 0.f;

  const int rbase = tile * 1024;
  float4 kv0, kv1, kv2, kv3;
  float mskK;
  {
    const float* rp = Kh + (size_t)(rbase + w * 16 + lm) * 64 + kl * 8;
    kv0 = *(const float4*)rp;        kv1 = *(const float4*)(rp + 4);
    kv2 = *(const float4*)(rp + 32); kv3 = *(const float4*)(rp + 36);
    mskK = mrow[rbase + w * 16 + lm];
  }

  for (int ch = 0; ch < 8; ++ch) {
    const int r0 = rbase + ch * 128;
    // opaque per-chunk pointer: blocks loop-invariant hoist of all 16 frag
    // loads into registers (r18 failure mode)
    const unsigned short* BxB = BxG + mh * 8192;
    asm volatile("" : "+s"(BxB));
    // ---- convert own K row regs -> hi/lo f16 A-frags (LOG2E folded) + diag ----
    half8 ah0, ah1, al0, al1;
    float diagv;
    {
      float scale = CNORM * LOG2E * mskK;
      float x[16] = {kv0.x, kv0.y, kv0.z, kv0.w, kv1.x, kv1.y, kv1.z, kv1.w,
                     kv2.x, kv2.y, kv2.z, kv2.w, kv3.x, kv3.y, kv3.z, kv3.w};
      float sq = 0.f;
#pragma unroll
      for (int e = 0; e < 16; ++e) {
        float y = x[e] * scale;
        _Float16 h = (_Float16)y;
        _Float16 lo = (_Float16)((y - (float)h) * 2048.0f);
        if (e < 8) { ah0[e] = h; al0[e] = lo; } else { ah1[e - 8] = h; al1[e - 8] = lo; }
        sq = fmaf(y, y, sq);
      }
      sq += __shfl_xor(sq, 16);
      sq += __shfl_xor(sq, 32);
      diagv = DGC * sq;   // = LOG2E * 0.5 * |x*CNORM|^2
    }
    // ---- prefetch next chunk's K rows ----
    {
      const int nr = rbase + ((ch + 1) & 7) * 128 + w * 16 + lm;
      const float* rp = Kh + (size_t)nr * 64 + kl * 8;
      kv0 = *(const float4*)rp;        kv1 = *(const float4*)(rp + 4);
      kv2 = *(const float4*)(rp + 32); kv3 = *(const float4*)(rp + 36);
      mskK = mrow[nr];
    }
    // ---- issue V loads (consumed after p1) ----
    float vv[16];
#pragma unroll
    for (int h = 0; h < 2; ++h) {
      int nb = (ksv0 * 2 + h) * 32 + klnv * 8;
#pragma unroll
      for (int j = 0; j < 8; ++j)
        vv[h * 8 + j] = Vh[(size_t)(r0 + nb + j) * 64 + dtv * 16 + lmv];
    }
    // ---- p1 fused with features: per j, 4 MFMAs -> exp2 -> bf16 -> Fs ----
    float dgv[4];
#pragma unroll
    for (int r = 0; r < 4; ++r)
      dgv[r] = __shfl(diagv, (l & 48) + kl * 4 + r);
#pragma unroll
    for (int j = 0; j < 8; ++j) {
      half8 b0 = *(const half8*)(BxB + (size_t)(((j * 2 + 0) * 64 + l) * 8));
      half8 b1 = *(const half8*)(BxB + (size_t)(((j * 2 + 1) * 64 + l) * 8));
      f32x4 a0 = {0.f, 0.f, 0.f, 0.f}, a1 = {0.f, 0.f, 0.f, 0.f};
      a0 = __builtin_amdgcn_mfma_f32_16x16x32_f16(ah0, b0, a0, 0, 0, 0);
      a0 = __builtin_amdgcn_mfma_f32_16x16x32_f16(ah1, b1, a0, 0, 0, 0);
      a1 = __builtin_amdgcn_mfma_f32_16x16x32_f16(al0, b0, a1, 0, 0, 0);
      a1 = __builtin_amdgcn_mfma_f32_16x16x32_f16(al1, b1, a1, 0, 0, 0);
      float x0 = fmaf(a1[0], INV2048, a0[0]);
      float x1 = fmaf(a1[1], INV2048, a0[1]);
      float x2 = fmaf(a1[2], INV2048, a0[2]);
      float x3 = fmaf(a1[3], INV2048, a0[3]);
      wm = fmaxf(wm, fmaxf(fmaxf(x0, x1), fmaxf(x2, x3)));
      float f0 = exp2hw(x0 - dgv[0]);
      float f1 = exp2hw(x1 - dgv[1]);
      float f2 = exp2hw(x2 - dgv[2]);
      float f3 = exp2hw(x3 - dgv[3]);
      kspart[j] += f0 + f1 + f2 + f3;
      *(uint2*)&Fs[(j * 16 + lm) * 140 + w * 16 + kl * 4] =
          make_uint2(cvtpk(f0, f1), cvtpk(f2, f3));
    }
    // ---- V -> VF (bf16 frag-linear) + masked V row-sum ----
#pragma unroll
    for (int h = 0; h < 2; ++h) {
      int ks = ksv0 * 2 + h;
      int nb = ks * 32 + klnv * 8;
      float4 m0 = *(const float4*)&mrow[r0 + nb];
      float4 m1 = *(const float4*)&mrow[r0 + nb + 4];
      float mk[8] = {m0.x, m0.y, m0.z, m0.w, m1.x, m1.y, m1.z, m1.w};
      float vm[8];
#pragma unroll
      for (int j = 0; j < 8; ++j) {
        vm[j] = vv[h * 8 + j] * mk[j];
        vsum += vm[j];
      }
      *(uint4*)&VF[((ks * 4 + dtv) * 64 + klnv * 16 + lmv) * 8] =
          make_uint4(cvtpk(vm[0], vm[1]), cvtpk(vm[2], vm[3]),
                     cvtpk(vm[4], vm[5]), cvtpk(vm[6], vm[7]));
    }
    __syncthreads();   // barrier 1: Fs + VF ready
    // ---- p2: ctx[m][d] += k'^T V; wave w owns m-rows w*16..+16 ----
#pragma unroll
    for (int ks = 0; ks < 4; ++ks) {
      union { short8 v; uint2 u[2]; } af;
      const int ab = (w * 16 + lm) * 140 + ks * 32 + kl * 8;
      af.u[0] = *(const uint2*)&Fs[ab];
      af.u[1] = *(const uint2*)&Fs[ab + 4];
#pragma unroll
      for (int dt = 0; dt < 4; ++dt) {
        short8 vb = *(const short8*)&VF[((ks * 4 + dt) * 64 + l) * 8];
        cacc[dt] = __builtin_amdgcn_mfma_f32_16x16x32_bf16(af.v, vb, cacc[dt], 0, 0, 0);
      }
    }
    __syncthreads();   // barrier 2: p2 reads done before next chunk's writes
  }
  // ---- epilogue (VF now dead -> aliased scratch) ----
#pragma unroll
  for (int j = 0; j < 8; ++j) {
    kspart[j] += __shfl_xor(kspart[j], 16);
    kspart[j] += __shfl_xor(kspart[j], 32);
  }
  if (l < 16) {
#pragma unroll
    for (int j = 0; j < 8; ++j) ksred[(j * 16 + l) * 8 + w] = kspart[j];
  }
  {
    wm = fmaxf(wm, __shfl_xor(wm, 1));  wm = fmaxf(wm, __shfl_xor(wm, 2));
    wm = fmaxf(wm, __shfl_xor(wm, 4));  wm = fmaxf(wm, __shfl_xor(wm, 8));
    wm = fmaxf(wm, __shfl_xor(wm, 16)); wm = fmaxf(wm, __shfl_xor(wm, 32));
    if (l == 0) wmax[w] = wm;
  }
  vred[tid] = vsum;
  __syncthreads();
  if (tid < 128) {
    float s = 0.f;
#pragma unroll
    for (int k = 0; k < 8; ++k) s += ksred[tid * 8 + k];
    ksump[(size_t)(bh * 16 + tl16) * 128 + tid] = s;
  }
  if (mh == 0 && tid < 64) {
    float vs = 0.f;
#pragma unroll
    for (int k = 0; k < 8; ++k)
      vs += vred[(k >> 2) * 256 + (tid >> 4) * 64 + (k & 3) * 16 + (tid & 15)];
    vsp[(size_t)(bh * 8 + tile) * 64 + tid] = vs;
  }
  if (tid == 0) {
    float bm = wmax[0];
#pragma unroll
    for (int i = 1; i < 8; ++i) bm = fmaxf(bm, wmax[i]);
    mxg[bh * 256 + 240 + tl16] = bm;   // log2-units max, packed into ksumG tail
  }
  float* cp = ctxp + (size_t)(bh * 16 + tl16) * 8192;
#pragma unroll
  for (int dt = 0; dt < 4; ++dt)
#pragma unroll
    for (int r = 0; r < 4; ++r)
      cp[(w * 16 + kl * 4 + r) * 64 + dt * 16 + lm] = cacc[dt][r];
}

// ---------------- kRedCtx: sum partials, scale exp2(-MX), eps terms ----------------
__global__ void kRedCtx(const float* __restrict__ ctxp, const float* __restrict__ ksump,
                        const float* __restrict__ vsp, unsigned short* __restrict__ CsG,
                        float* __restrict__ ksumG) {
  __shared__ __align__(16) float ctxL[16384];
  __shared__ float vsL[64];
  const int bh = blockIdx.x, t = threadIdx.x;   // 256 threads
  float MX = -3e38f;
#pragma unroll
  for (int i = 0; i < 16; ++i) MX = fmaxf(MX, ksumG[bh * 256 + 240 + i]);  // packed maxes
  const float fsc = exp2hw(-MX);
  __syncthreads();   // all threads read packed maxes before any ksumG writes
#pragma unroll
  for (int i = 0; i < 16; ++i) {
    int idx4 = t + i * 256;                 // float4 index; m = idx4>>4
    int mhi = (idx4 >> 11) & 1;             // m-half
    int loc = idx4 & 2047;
    float4 s = make_float4(0.f, 0.f, 0.f, 0.f);
#pragma unroll
    for (int tl = 0; tl < 8; ++tl) {
      float4 a = ((const float4*)(ctxp + (size_t)(bh * 16 + tl * 2 + mhi) * 8192))[loc];
      s.x += a.x; s.y += a.y; s.z += a.z; s.w += a.w;
    }
    s.x *= fsc; s.y *= fsc; s.z *= fsc; s.w *= fsc;
    ((float4*)ctxL)[idx4] = s;
  }
  {
    int mhi = t >> 7, loc = t & 127;
    float ks = 0.f;
#pragma unroll
    for (int tl = 0; tl < 8; ++tl)
      ks += ksump[(size_t)(bh * 16 + tl * 2 + mhi) * 128 + loc];
    ksumG[bh * 256 + t] = fsc * ks + FEPS * (float)BN;
  }
  if (t < 64) {
    float vs = 0.f;
#pragma unroll
    for (int tl = 0; tl < 8; ++tl) vs += vsp[(size_t)(bh * 8 + tl) * 64 + t];
    vsL[t] = vs;
  }
  __syncthreads();
#pragma unroll
  for (int i = 0; i < 8; ++i) {
    int slot = t + i * 256;   // [dt 4][s 8][lane 64]
    int l = slot & 63, s = (slot >> 6) & 7, dt = slot >> 9;
    int d = dt * 16 + (l & 15);
    int mb = s * 32 + (l >> 4) * 8;
    float ve = FEPS * vsL[d];
    unsigned short o[8];
#pragma unroll
    for (int j = 0; j < 8; ++j) o[j] = f2bf(ctxL[(mb + j) * 64 + d] + ve);
    *(uint4*)(CsG + (size_t)bh * 16384 + (size_t)slot * 8) =
        make_uint4(pk2(o[0], o[1]), pk2(o[2], o[3]), pk2(o[4], o[5]), pk2(o[6], o[7]));
  }
}

// ---------------- kOut: wave-private q pipeline (r19, unchanged) ----------------
__global__ void __launch_bounds__(512, 1)
kOut(const float* __restrict__ Qin, const unsigned short* __restrict__ BxG,
     const unsigned short* __restrict__ CsG, const float* __restrict__ ksumG,
     float* __restrict__ outp) {
  __shared__ __align__(16) unsigned short BxH[16384];    // 32 KB
  __shared__ __align__(16) unsigned short Ff[128 * FFS]; // 66.6 KB q-features bf16
  __shared__ float den[128];                             // 1/denominator per row
  const int tid = threadIdx.x;
  int bh, tile;
  xcd_map<8>(bh, tile);
  const float* Qh = Qin + (size_t)bh * BN * DD;
  const unsigned short* CsB = CsG + (size_t)bh * 16384;
  const int w = tid >> 6, l = tid & 63, lm = l & 15, kl = l >> 4;
#pragma unroll
  for (int i = 0; i < 4; ++i)
    ((uint4*)BxH)[tid + i * 512] = ((const uint4*)BxG)[tid + i * 512];
  short8 cb[8];
#pragma unroll
  for (int s = 0; s < 8; ++s)
    cb[s] = *(const short8*)(CsB + (size_t)((((w >> 1) * 8 + s) * 64 + l) * 8));
  float kss[16];
#pragma unroll
  for (int j = 0; j < 16; ++j) kss[j] = ksumG[bh * 256 + j * 16 + lm];
  // peel: q regs for chunk 0
  float4 qv0, qv1, qv2, qv3;
  {
    const float* rp = Qh + (size_t)(tile * 1024 + w * 16 + lm) * 64 + kl * 8;
    qv0 = *(const float4*)rp;        qv1 = *(const float4*)(rp + 4);
    qv2 = *(const float4*)(rp + 32); qv3 = *(const float4*)(rp + 36);
  }
  __syncthreads();   // BxH ready

  for (int ch = 0; ch < 8; ++ch) {
    const int r0 = tile * 1024 + ch * 128;
    // ---- convert own q row regs -> hi/lo f16 A-frags + diag ----
    half8 ah0, ah1, al0, al1;
    float sq = 0.f;
    {
      const float scale = CNORM * LOG2E;
      float x[16] = {qv0.x, qv0.y, qv0.z, qv0.w, qv1.x, qv1.y, qv1.z, qv1.w,
                     qv2.x, qv2.y, qv2.z, qv2.w, qv3.x, qv3.y, qv3.z, qv3.w};
#pragma unroll
      for (int e = 0; e < 16; ++e) {
        float y = x[e] * scale;
        _Float16 h = (_Float16)y;
        _Float16 lo = (_Float16)((y - (float)h) * 2048.0f);
        if (e < 8) { ah0[e] = h; al0[e] = lo; } else { ah1[e - 8] = h; al1[e - 8] = lo; }
        sq = fmaf(y, y, sq);
      }
      sq += __shfl_xor(sq, 16);
      sq += __shfl_xor(sq, 32);
    }
    const float diagv = DGC * sq;   // log2 units
    // ---- prefetch next chunk's q rows (hides HBM latency under p1) ----
    {
      const int nr = tile * 1024 + ((ch + 1) & 7) * 128 + w * 16 + lm;
      const float* rp = Qh + (size_t)nr * 64 + kl * 8;
      qv0 = *(const float4*)rp;        qv1 = *(const float4*)(rp + 4);
      qv2 = *(const float4*)(rp + 32); qv3 = *(const float4*)(rp + 36);
    }
    f32x4 accC[16];
#pragma unroll
    for (int j = 0; j < 16; ++j) {
      half8 b0 = *(const half8*)&BxH[((j * 2 + 0) * 64 + l) * 8];
      half8 b1 = *(const half8*)&BxH[((j * 2 + 1) * 64 + l) * 8];
      f32x4 acc0 = {0.f, 0.f, 0.f, 0.f}, acc1 = {0.f, 0.f, 0.f, 0.f};
      acc0 = __builtin_amdgcn_mfma_f32_16x16x32_f16(ah0, b0, acc0, 0, 0, 0);
      acc0 = __builtin_amdgcn_mfma_f32_16x16x32_f16(ah1, b1, acc0, 0, 0, 0);
      acc1 = __builtin_amdgcn_mfma_f32_16x16x32_f16(al0, b0, acc1, 0, 0, 0);
      acc1 = __builtin_amdgcn_mfma_f32_16x16x32_f16(al1, b1, acc1, 0, 0, 0);
#pragma unroll
      for (int r = 0; r < 4; ++r) accC[j][r] = fmaf(acc1[r], INV2048, acc0[r]);
    }
    float mrow[4];
#pragma unroll
    for (int r = 0; r < 4; ++r) {
      float m0 = accC[0][r];
#pragma unroll
      for (int j = 1; j < 16; ++j) m0 = fmaxf(m0, accC[j][r]);
      m0 = fmaxf(m0, __shfl_xor(m0, 1));
      m0 = fmaxf(m0, __shfl_xor(m0, 2));
      m0 = fmaxf(m0, __shfl_xor(m0, 4));
      m0 = fmaxf(m0, __shfl_xor(m0, 8));
      mrow[r] = m0;
    }
    float dgv[4], dnn[4] = {0.f, 0.f, 0.f, 0.f};
#pragma unroll
    for (int r = 0; r < 4; ++r)
      dgv[r] = __shfl(diagv, (l & 48) + kl * 4 + r) + mrow[r];
#pragma unroll
    for (int j = 0; j < 16; ++j) {
#pragma unroll
      for (int r = 0; r < 4; ++r) {
        float q = exp2hw(accC[j][r] - dgv[r]) + FEPS;
        unsigned short qh = f2bf(q);
        Ff[(w * 16 + kl * 4 + r) * FFS + j * 16 + lm] = qh;
        dnn[r] += bf2f(qh) * kss[j];
      }
    }
#pragma unroll
    for (int r = 0; r < 4; ++r) {
      dnn[r] += __shfl_xor(dnn[r], 1); dnn[r] += __shfl_xor(dnn[r], 2);
      dnn[r] += __shfl_xor(dnn[r], 4); dnn[r] += __shfl_xor(dnn[r], 8);
    }
    if (lm == 0) {
#pragma unroll
      for (int r = 0; r < 4; ++r) den[w * 16 + kl * 4 + r] = 1.0f / dnn[r];
    }
    __syncthreads();   // features + den ready for all waves
    const int prow = (w & 1) * 64, pd = (w >> 1) * 16;
    f32x4 oacc[4];
#pragma unroll
    for (int fr = 0; fr < 4; ++fr) oacc[fr] = f32x4{0.f, 0.f, 0.f, 0.f};
#pragma unroll
    for (int s = 0; s < 8; ++s) {
#pragma unroll
      for (int fr = 0; fr < 4; ++fr) {
        short8 af = *(const short8*)&Ff[(prow + fr * 16 + lm) * FFS + s * 32 + kl * 8];
        oacc[fr] = __builtin_amdgcn_mfma_f32_16x16x32_bf16(af, cb[s], oacc[fr], 0, 0, 0);
      }
    }
#pragma unroll
    for (int fr = 0; fr < 4; ++fr) {
#pragma unroll
      for (int r = 0; r < 4; ++r) {
        int n = prow + fr * 16 + kl * 4 + r;
        outp[((size_t)bh * BN + r0 + n) * 64 + pd + lm] = oacc[fr][r] * den[n];
      }
    }
    __syncthreads();   // p2 reads done before next chunk overwrites Ff
  }
}

extern "C" void kernel_launch(void* const* d_in, const int* in_sizes, int n_in,
                              void* d_out, int out_size, void* d_ws, size_t ws_size,
                              hipStream_t stream) {
  const float* Q    = (const float*)d_in[0];
  const float* K    = (const float*)d_in[1];
  const float* V    = (const float*)d_in[2];
  const float* mask = (const float*)d_in[3];
  const float* proj = (const float*)d_in[4];
  float* out = (float*)d_out;
  float* ws = (float*)d_ws;

  unsigned short* wBx = (unsigned short*)(ws + OFF_BX);
  unsigned short* wCs = (unsigned short*)(ws + OFF_CS);
  float* wKsump = ws + OFF_KSUMP;
  float* wKsumG = ws + OFF_KSUMG;
  float* wVsp   = ws + OFF_VSP;
  float* wCtxp  = ws + OFF_CTXP;

  kPrep<<<8, 256, 0, stream>>>(proj, wBx);
  kCtx<<<dim3(16, NHEADS), 512, 0, stream>>>(K, V, mask, wBx, wCtxp, wKsump, wKsumG, wVsp);
  kRedCtx<<<NHEADS, 256, 0, stream>>>(wCtxp, wKsump, wVsp, wCs, wKsumG);
  kOut<<<dim3(8, NHEADS), 512, 0, stream>>>(Q, wBx, wCs, wKsumG, out);
}

// Round 11
// 133.361 us; speedup vs baseline: 2.2826x; 2.2826x over previous
//
#include <hip/hip_runtime.h>

// Performer (FAVOR+) self-attention. B=4 H=8 N=8192 D=64 M=256.
// Round 21 = exact revert to r19 (best measured: 133.4 us) after r20's
// tripwire fired (WRITE_SIZE 379 MB = spill; VGPR 40).
// Confirmed-4x rule: no global fragment streams inside unrolled MFMA loops;
// no register caps (<~128) while accC[16] is live; asm pointer-opacity does
// NOT prevent within-loop hoisting of unrolled frag loads.
// kCtx: 512 blocks x 512 thr, 73.5 KB LDS, 2 blocks/CU, exp2+cvtpk diet.
// kOut: 256 blocks x 512 thr, 99 KB LDS, 1 block/CU, Q prefetch, Ff stride 260.
// kPrep -> kCtx -> kRedCtx -> kOut

typedef __attribute__((ext_vector_type(8))) short short8;
typedef __attribute__((ext_vector_type(8))) _Float16 half8;
typedef __attribute__((ext_vector_type(4))) float f32x4;

namespace {
constexpr int BN = 8192, DD = 64, MM = 256, NHEADS = 32;
constexpr float CNORM = 0.35355339059327373f;   // D^-0.25
constexpr float LOG2E = 1.4426950408889634f;
constexpr float DGC   = 0.34657359027997264f;   // 0.5/LOG2E
constexpr float FEPS  = 1e-4f;
constexpr float INV2048 = 4.8828125e-4f;
constexpr int FFS = 260;                        // kOut Ff stride (ushorts)

// workspace layout in floats (total 4,555,008 f = 18.22 MB)
constexpr size_t OFF_BX    = 0;         // 16384 ushort = 8192 f
constexpr size_t OFF_CS    = 8192;      // 32*16384 ushort -> ends 270336
constexpr size_t OFF_KSUMP = 270336;    // 32*16*128 = 65536 -> 335872
constexpr size_t OFF_KSUMG = 335872;    // 32*256 = 8192 -> 344064 (mx packed @ +240..255/bh)
constexpr size_t OFF_VSP   = 344320;    // 32*8*64 = 16384 -> 360704
constexpr size_t OFF_CTXP  = 360704;    // 32*16*8192 = 4194304 -> 4555008
}

__device__ __forceinline__ unsigned short f2bf(float f) {
  unsigned u = __float_as_uint(f);
  u += 0x7fffu + ((u >> 16) & 1u);
  return (unsigned short)(u >> 16);
}
__device__ __forceinline__ float bf2f(unsigned short h) {
  return __uint_as_float(((unsigned)h) << 16);
}
__device__ __forceinline__ unsigned pk2(unsigned short a, unsigned short b) {
  return (unsigned)a | ((unsigned)b << 16);
}
__device__ __forceinline__ unsigned short f2h(float f) {
  _Float16 h = (_Float16)f;
  return __builtin_bit_cast(unsigned short, h);
}
__device__ __forceinline__ float exp2hw(float x) {
  float r;
  asm("v_exp_f32 %0, %1" : "=v"(r) : "v"(x));
  return r;
}
__device__ __forceinline__ unsigned cvtpk(float lo, float hi) {
  unsigned r;
  asm("v_cvt_pk_bf16_f32 %0, %1, %2" : "=v"(r) : "v"(lo), "v"(hi));
  return r;
}

// XCD swizzle: linear id -> (bh, tile); each XCD owns 4 consecutive heads.
template <int T>
__device__ __forceinline__ void xcd_map(int& bh, int& tile) {
  int id = blockIdx.y * T + blockIdx.x;
  int xcd = id & 7, s = id >> 3;
  bh = xcd * 4 + s / T;
  tile = s % T;
}

// ---------------- kPrep: proj -> single-f16 frag stream (32 KB) ----------------
// BxG[mt 16][kb 2][lane 64][8 f16]; kb = K-half (d 0-31 / 32-63).
__global__ void kPrep(const float* __restrict__ proj, unsigned short* __restrict__ BxG) {
  int s = blockIdx.x * 256 + threadIdx.x;   // 0..2047
  int l = s & 63, kb = (s >> 6) & 1, mt = s >> 7;
  int n = mt * 16 + (l & 15);
  int k0 = kb * 32 + (l >> 4) * 8;
  unsigned short o[8];
#pragma unroll
  for (int j = 0; j < 8; ++j) o[j] = f2h(proj[n * 64 + k0 + j]);
  *(uint4*)(BxG + (size_t)s * 8) =
      make_uint4(pk2(o[0], o[1]), pk2(o[2], o[3]), pk2(o[4], o[5]), pk2(o[6], o[7]));
}

// ---------------- kCtx: unscaled k-feature pipeline -> ctx/ksum partials + max ----------------
// Block = (bh, tile, mh): 1024 rows (8 chunks x 128), m-half mh*128..+128.
__global__ void __launch_bounds__(512, 4)
kCtx(const float* __restrict__ Kin, const float* __restrict__ Vin,
     const float* __restrict__ mask, const unsigned short* __restrict__ BxG,
     float* __restrict__ ctxp, float* __restrict__ ksump,
     float* __restrict__ mxg, float* __restrict__ vsp) {
  __shared__ __align__(16) unsigned short BxH[8192];      // 16 KB (this m-half of proj)
  __shared__ __align__(16) unsigned short Fs[128 * 140];  // 35 KB features [m][n], stride 140
  __shared__ __align__(16) unsigned short VF[16 * 64 * 8];// 16 KB [ks4][dt4][lane64][8] bf16
  __shared__ float wmax[8];
  __shared__ float ksred[1024];
  __shared__ float vred[512];
  const int tid = threadIdx.x;
  int bh, tl16;
  xcd_map<16>(bh, tl16);
  const int tile = tl16 >> 1, mh = tl16 & 1;
  const int b = bh >> 3;
  const float* Kh = Kin + (size_t)bh * BN * DD;
  const float* Vh = Vin + (size_t)bh * BN * DD;
  const float* mrow = mask + (size_t)b * BN;
#pragma unroll
  for (int i = 0; i < 2; ++i)
    ((uint4*)BxH)[tid + i * 512] = ((const uint4*)BxG)[mh * 1024 + tid + i * 512];
  const int w = tid >> 6, l = tid & 63, lm = l & 15, kl = l >> 4;
  const int lmv = tid & 15, klnv = (tid >> 4) & 3, dtv = (tid >> 6) & 3, ksv0 = tid >> 8;

  f32x4 cacc[4];
#pragma unroll
  for (int dt = 0; dt < 4; ++dt) cacc[dt] = f32x4{0.f, 0.f, 0.f, 0.f};
  float kspart[8] = {0.f, 0.f, 0.f, 0.f, 0.f, 0.f, 0.f, 0.f};
  float wm = -3e38f, vsum = 0.f;

  const int rbase = tile * 1024;
  float4 kv0, kv1, kv2, kv3;
  float mskK;
  {
    const float* rp = Kh + (size_t)(rbase + w * 16 + lm) * 64 + kl * 8;
    kv0 = *(const float4*)rp;        kv1 = *(const float4*)(rp + 4);
    kv2 = *(const float4*)(rp + 32); kv3 = *(const float4*)(rp + 36);
    mskK = mrow[rbase + w * 16 + lm];
  }
  __syncthreads();   // BxH ready

  for (int ch = 0; ch < 8; ++ch) {
    const int r0 = rbase + ch * 128;
    // ---- convert own K row regs -> hi/lo f16 A-frags (LOG2E folded) + diag ----
    half8 ah0, ah1, al0, al1;
    float diagv;
    {
      float scale = CNORM * LOG2E * mskK;
      float x[16] = {kv0.x, kv0.y, kv0.z, kv0.w, kv1.x, kv1.y, kv1.z, kv1.w,
                     kv2.x, kv2.y, kv2.z, kv2.w, kv3.x, kv3.y, kv3.z, kv3.w};
      float sq = 0.f;
#pragma unroll
      for (int e = 0; e < 16; ++e) {
        float y = x[e] * scale;
        _Float16 h = (_Float16)y;
        _Float16 lo = (_Float16)((y - (float)h) * 2048.0f);
        if (e < 8) { ah0[e] = h; al0[e] = lo; } else { ah1[e - 8] = h; al1[e - 8] = lo; }
        sq = fmaf(y, y, sq);
      }
      sq += __shfl_xor(sq, 16);
      sq += __shfl_xor(sq, 32);
      diagv = DGC * sq;   // = LOG2E * 0.5 * |x*CNORM|^2
    }
    // ---- prefetch next chunk's K rows ----
    {
      const int nr = rbase + ((ch + 1) & 7) * 128 + w * 16 + lm;
      const float* rp = Kh + (size_t)nr * 64 + kl * 8;
      kv0 = *(const float4*)rp;        kv1 = *(const float4*)(rp + 4);
      kv2 = *(const float4*)(rp + 32); kv3 = *(const float4*)(rp + 36);
      mskK = mrow[nr];
    }
    // ---- issue V loads (consumed after p1) ----
    float vv[16];
#pragma unroll
    for (int h = 0; h < 2; ++h) {
      int nb = (ksv0 * 2 + h) * 32 + klnv * 8;
#pragma unroll
      for (int j = 0; j < 8; ++j)
        vv[h * 8 + j] = Vh[(size_t)(r0 + nb + j) * 64 + dtv * 16 + lmv];
    }
    // ---- p1 fused with features: per j, 4 MFMAs -> exp2 -> bf16 -> Fs ----
    float dgv[4];
#pragma unroll
    for (int r = 0; r < 4; ++r)
      dgv[r] = __shfl(diagv, (l & 48) + kl * 4 + r);
#pragma unroll
    for (int j = 0; j < 8; ++j) {
      half8 b0 = *(const half8*)&BxH[((j * 2 + 0) * 64 + l) * 8];
      half8 b1 = *(const half8*)&BxH[((j * 2 + 1) * 64 + l) * 8];
      f32x4 a0 = {0.f, 0.f, 0.f, 0.f}, a1 = {0.f, 0.f, 0.f, 0.f};
      a0 = __builtin_amdgcn_mfma_f32_16x16x32_f16(ah0, b0, a0, 0, 0, 0);
      a0 = __builtin_amdgcn_mfma_f32_16x16x32_f16(ah1, b1, a0, 0, 0, 0);
      a1 = __builtin_amdgcn_mfma_f32_16x16x32_f16(al0, b0, a1, 0, 0, 0);
      a1 = __builtin_amdgcn_mfma_f32_16x16x32_f16(al1, b1, a1, 0, 0, 0);
      float x0 = fmaf(a1[0], INV2048, a0[0]);
      float x1 = fmaf(a1[1], INV2048, a0[1]);
      float x2 = fmaf(a1[2], INV2048, a0[2]);
      float x3 = fmaf(a1[3], INV2048, a0[3]);
      wm = fmaxf(wm, fmaxf(fmaxf(x0, x1), fmaxf(x2, x3)));
      float f0 = exp2hw(x0 - dgv[0]);
      float f1 = exp2hw(x1 - dgv[1]);
      float f2 = exp2hw(x2 - dgv[2]);
      float f3 = exp2hw(x3 - dgv[3]);
      kspart[j] += f0 + f1 + f2 + f3;
      *(uint2*)&Fs[(j * 16 + lm) * 140 + w * 16 + kl * 4] =
          make_uint2(cvtpk(f0, f1), cvtpk(f2, f3));
    }
    // ---- V -> VF (bf16 frag-linear) + masked V row-sum ----
#pragma unroll
    for (int h = 0; h < 2; ++h) {
      int ks = ksv0 * 2 + h;
      int nb = ks * 32 + klnv * 8;
      float4 m0 = *(const float4*)&mrow[r0 + nb];
      float4 m1 = *(const float4*)&mrow[r0 + nb + 4];
      float mk[8] = {m0.x, m0.y, m0.z, m0.w, m1.x, m1.y, m1.z, m1.w};
      float vm[8];
#pragma unroll
      for (int j = 0; j < 8; ++j) {
        vm[j] = vv[h * 8 + j] * mk[j];
        vsum += vm[j];
      }
      *(uint4*)&VF[((ks * 4 + dtv) * 64 + klnv * 16 + lmv) * 8] =
          make_uint4(cvtpk(vm[0], vm[1]), cvtpk(vm[2], vm[3]),
                     cvtpk(vm[4], vm[5]), cvtpk(vm[6], vm[7]));
    }
    __syncthreads();   // barrier 1: Fs + VF ready
    // ---- p2: ctx[m][d] += k'^T V; wave w owns m-rows w*16..+16 ----
#pragma unroll
    for (int ks = 0; ks < 4; ++ks) {
      union { short8 v; uint2 u[2]; } af;
      const int ab = (w * 16 + lm) * 140 + ks * 32 + kl * 8;
      af.u[0] = *(const uint2*)&Fs[ab];
      af.u[1] = *(const uint2*)&Fs[ab + 4];
#pragma unroll
      for (int dt = 0; dt < 4; ++dt) {
        short8 vb = *(const short8*)&VF[((ks * 4 + dt) * 64 + l) * 8];
        cacc[dt] = __builtin_amdgcn_mfma_f32_16x16x32_bf16(af.v, vb, cacc[dt], 0, 0, 0);
      }
    }
    __syncthreads();   // barrier 2: p2 reads done before next chunk's writes
  }
  // ---- epilogue ----
#pragma unroll
  for (int j = 0; j < 8; ++j) {
    kspart[j] += __shfl_xor(kspart[j], 16);
    kspart[j] += __shfl_xor(kspart[j], 32);
  }
  if (l < 16) {
#pragma unroll
    for (int j = 0; j < 8; ++j) ksred[(j * 16 + l) * 8 + w] = kspart[j];
  }
  {
    wm = fmaxf(wm, __shfl_xor(wm, 1));  wm = fmaxf(wm, __shfl_xor(wm, 2));
    wm = fmaxf(wm, __shfl_xor(wm, 4));  wm = fmaxf(wm, __shfl_xor(wm, 8));
    wm = fmaxf(wm, __shfl_xor(wm, 16)); wm = fmaxf(wm, __shfl_xor(wm, 32));
    if (l == 0) wmax[w] = wm;
  }
  vred[tid] = vsum;
  __syncthreads();
  if (tid < 128) {
    float s = 0.f;
#pragma unroll
    for (int k = 0; k < 8; ++k) s += ksred[tid * 8 + k];
    ksump[(size_t)(bh * 16 + tl16) * 128 + tid] = s;
  }
  if (mh == 0 && tid < 64) {
    float vs = 0.f;
#pragma unroll
    for (int k = 0; k < 8; ++k)
      vs += vred[(k >> 2) * 256 + (tid >> 4) * 64 + (k & 3) * 16 + (tid & 15)];
    vsp[(size_t)(bh * 8 + tile) * 64 + tid] = vs;
  }
  if (tid == 0) {
    float bm = wmax[0];
#pragma unroll
    for (int i = 1; i < 8; ++i) bm = fmaxf(bm, wmax[i]);
    mxg[bh * 256 + 240 + tl16] = bm;   // log2-units max, packed into ksumG tail
  }
  float* cp = ctxp + (size_t)(bh * 16 + tl16) * 8192;
#pragma unroll
  for (int dt = 0; dt < 4; ++dt)
#pragma unroll
    for (int r = 0; r < 4; ++r)
      cp[(w * 16 + kl * 4 + r) * 64 + dt * 16 + lm] = cacc[dt][r];
}

// ---------------- kRedCtx: sum partials, scale exp2(-MX), eps terms ----------------
__global__ void kRedCtx(const float* __restrict__ ctxp, const float* __restrict__ ksump,
                        const float* __restrict__ vsp, unsigned short* __restrict__ CsG,
                        float* __restrict__ ksumG) {
  __shared__ __align__(16) float ctxL[16384];
  __shared__ float vsL[64];
  const int bh = blockIdx.x, t = threadIdx.x;   // 256 threads
  float MX = -3e38f;
#pragma unroll
  for (int i = 0; i < 16; ++i) MX = fmaxf(MX, ksumG[bh * 256 + 240 + i]);  // packed maxes
  const float fsc = exp2hw(-MX);
  __syncthreads();   // all threads read packed maxes before any ksumG writes
#pragma unroll
  for (int i = 0; i < 16; ++i) {
    int idx4 = t + i * 256;                 // float4 index; m = idx4>>4
    int mhi = (idx4 >> 11) & 1;             // m-half
    int loc = idx4 & 2047;
    float4 s = make_float4(0.f, 0.f, 0.f, 0.f);
#pragma unroll
    for (int tl = 0; tl < 8; ++tl) {
      float4 a = ((const float4*)(ctxp + (size_t)(bh * 16 + tl * 2 + mhi) * 8192))[loc];
      s.x += a.x; s.y += a.y; s.z += a.z; s.w += a.w;
    }
    s.x *= fsc; s.y *= fsc; s.z *= fsc; s.w *= fsc;
    ((float4*)ctxL)[idx4] = s;
  }
  {
    int mhi = t >> 7, loc = t & 127;
    float ks = 0.f;
#pragma unroll
    for (int tl = 0; tl < 8; ++tl)
      ks += ksump[(size_t)(bh * 16 + tl * 2 + mhi) * 128 + loc];
    ksumG[bh * 256 + t] = fsc * ks + FEPS * (float)BN;
  }
  if (t < 64) {
    float vs = 0.f;
#pragma unroll
    for (int tl = 0; tl < 8; ++tl) vs += vsp[(size_t)(bh * 8 + tl) * 64 + t];
    vsL[t] = vs;
  }
  __syncthreads();
#pragma unroll
  for (int i = 0; i < 8; ++i) {
    int slot = t + i * 256;   // [dt 4][s 8][lane 64]
    int l = slot & 63, s = (slot >> 6) & 7, dt = slot >> 9;
    int d = dt * 16 + (l & 15);
    int mb = s * 32 + (l >> 4) * 8;
    float ve = FEPS * vsL[d];
    unsigned short o[8];
#pragma unroll
    for (int j = 0; j < 8; ++j) o[j] = f2bf(ctxL[(mb + j) * 64 + d] + ve);
    *(uint4*)(CsG + (size_t)bh * 16384 + (size_t)slot * 8) =
        make_uint4(pk2(o[0], o[1]), pk2(o[2], o[3]), pk2(o[4], o[5]), pk2(o[6], o[7]));
  }
}

// ---------------- kOut: wave-private q pipeline (Q prefetch + Ff stride 260) ----------------
// 256 blocks (8 tiles x 32 bh), 512 thr, 8 chunks x 128 rows. p1: wave w owns
// rows w*16..+16, A-frags in regs from global Q (prefetched); rowmax/diag/
// denominator in-wave; 2 barriers per chunk.
__global__ void __launch_bounds__(512, 1)
kOut(const float* __restrict__ Qin, const unsigned short* __restrict__ BxG,
     const unsigned short* __restrict__ CsG, const float* __restrict__ ksumG,
     float* __restrict__ outp) {
  __shared__ __align__(16) unsigned short BxH[16384];    // 32 KB
  __shared__ __align__(16) unsigned short Ff[128 * FFS]; // 66.6 KB q-features bf16
  __shared__ float den[128];                             // 1/denominator per row
  const int tid = threadIdx.x;
  int bh, tile;
  xcd_map<8>(bh, tile);
  const float* Qh = Qin + (size_t)bh * BN * DD;
  const unsigned short* CsB = CsG + (size_t)bh * 16384;
  const int w = tid >> 6, l = tid & 63, lm = l & 15, kl = l >> 4;
#pragma unroll
  for (int i = 0; i < 4; ++i)
    ((uint4*)BxH)[tid + i * 512] = ((const uint4*)BxG)[tid + i * 512];
  short8 cb[8];
#pragma unroll
  for (int s = 0; s < 8; ++s)
    cb[s] = *(const short8*)(CsB + (size_t)((((w >> 1) * 8 + s) * 64 + l) * 8));
  float kss[16];
#pragma unroll
  for (int j = 0; j < 16; ++j) kss[j] = ksumG[bh * 256 + j * 16 + lm];
  // peel: q regs for chunk 0
  float4 qv0, qv1, qv2, qv3;
  {
    const float* rp = Qh + (size_t)(tile * 1024 + w * 16 + lm) * 64 + kl * 8;
    qv0 = *(const float4*)rp;        qv1 = *(const float4*)(rp + 4);
    qv2 = *(const float4*)(rp + 32); qv3 = *(const float4*)(rp + 36);
  }
  __syncthreads();   // BxH ready

  for (int ch = 0; ch < 8; ++ch) {
    const int r0 = tile * 1024 + ch * 128;
    // ---- convert own q row regs -> hi/lo f16 A-frags + diag ----
    half8 ah0, ah1, al0, al1;
    float sq = 0.f;
    {
      const float scale = CNORM * LOG2E;
      float x[16] = {qv0.x, qv0.y, qv0.z, qv0.w, qv1.x, qv1.y, qv1.z, qv1.w,
                     qv2.x, qv2.y, qv2.z, qv2.w, qv3.x, qv3.y, qv3.z, qv3.w};
#pragma unroll
      for (int e = 0; e < 16; ++e) {
        float y = x[e] * scale;
        _Float16 h = (_Float16)y;
        _Float16 lo = (_Float16)((y - (float)h) * 2048.0f);
        if (e < 8) { ah0[e] = h; al0[e] = lo; } else { ah1[e - 8] = h; al1[e - 8] = lo; }
        sq = fmaf(y, y, sq);
      }
      sq += __shfl_xor(sq, 16);
      sq += __shfl_xor(sq, 32);
    }
    const float diagv = DGC * sq;   // log2 units
    // ---- prefetch next chunk's q rows (hides HBM latency under p1) ----
    {
      const int nr = tile * 1024 + ((ch + 1) & 7) * 128 + w * 16 + lm;
      const float* rp = Qh + (size_t)nr * 64 + kl * 8;
      qv0 = *(const float4*)rp;        qv1 = *(const float4*)(rp + 4);
      qv2 = *(const float4*)(rp + 32); qv3 = *(const float4*)(rp + 36);
    }
    f32x4 accC[16];
#pragma unroll
    for (int j = 0; j < 16; ++j) {
      half8 b0 = *(const half8*)&BxH[((j * 2 + 0) * 64 + l) * 8];
      half8 b1 = *(const half8*)&BxH[((j * 2 + 1) * 64 + l) * 8];
      f32x4 acc0 = {0.f, 0.f, 0.f, 0.f}, acc1 = {0.f, 0.f, 0.f, 0.f};
      acc0 = __builtin_amdgcn_mfma_f32_16x16x32_f16(ah0, b0, acc0, 0, 0, 0);
      acc0 = __builtin_amdgcn_mfma_f32_16x16x32_f16(ah1, b1, acc0, 0, 0, 0);
      acc1 = __builtin_amdgcn_mfma_f32_16x16x32_f16(al0, b0, acc1, 0, 0, 0);
      acc1 = __builtin_amdgcn_mfma_f32_16x16x32_f16(al1, b1, acc1, 0, 0, 0);
#pragma unroll
      for (int r = 0; r < 4; ++r) accC[j][r] = fmaf(acc1[r], INV2048, acc0[r]);
    }
    float mrow[4];
#pragma unroll
    for (int r = 0; r < 4; ++r) {
      float m0 = accC[0][r];
#pragma unroll
      for (int j = 1; j < 16; ++j) m0 = fmaxf(m0, accC[j][r]);
      m0 = fmaxf(m0, __shfl_xor(m0, 1));
      m0 = fmaxf(m0, __shfl_xor(m0, 2));
      m0 = fmaxf(m0, __shfl_xor(m0, 4));
      m0 = fmaxf(m0, __shfl_xor(m0, 8));
      mrow[r] = m0;
    }
    float dgv[4], dnn[4] = {0.f, 0.f, 0.f, 0.f};
#pragma unroll
    for (int r = 0; r < 4; ++r)
      dgv[r] = __shfl(diagv, (l & 48) + kl * 4 + r) + mrow[r];
#pragma unroll
    for (int j = 0; j < 16; ++j) {
#pragma unroll
      for (int r = 0; r < 4; ++r) {
        float q = exp2hw(accC[j][r] - dgv[r]) + FEPS;
        unsigned short qh = f2bf(q);
        Ff[(w * 16 + kl * 4 + r) * FFS + j * 16 + lm] = qh;
        dnn[r] += bf2f(qh) * kss[j];
      }
    }
#pragma unroll
    for (int r = 0; r < 4; ++r) {
      dnn[r] += __shfl_xor(dnn[r], 1); dnn[r] += __shfl_xor(dnn[r], 2);
      dnn[r] += __shfl_xor(dnn[r], 4); dnn[r] += __shfl_xor(dnn[r], 8);
    }
    if (lm == 0) {
#pragma unroll
      for (int r = 0; r < 4; ++r) den[w * 16 + kl * 4 + r] = 1.0f / dnn[r];
    }
    __syncthreads();   // features + den ready for all waves
    const int prow = (w & 1) * 64, pd = (w >> 1) * 16;
    f32x4 oacc[4];
#pragma unroll
    for (int fr = 0; fr < 4; ++fr) oacc[fr] = f32x4{0.f, 0.f, 0.f, 0.f};
#pragma unroll
    for (int s = 0; s < 8; ++s) {
#pragma unroll
      for (int fr = 0; fr < 4; ++fr) {
        short8 af = *(const short8*)&Ff[(prow + fr * 16 + lm) * FFS + s * 32 + kl * 8];
        oacc[fr] = __builtin_amdgcn_mfma_f32_16x16x32_bf16(af, cb[s], oacc[fr], 0, 0, 0);
      }
    }
#pragma unroll
    for (int fr = 0; fr < 4; ++fr) {
#pragma unroll
      for (int r = 0; r < 4; ++r) {
        int n = prow + fr * 16 + kl * 4 + r;
        outp[((size_t)bh * BN + r0 + n) * 64 + pd + lm] = oacc[fr][r] * den[n];
      }
    }
    __syncthreads();   // p2 reads done before next chunk overwrites Ff
  }
}

extern "C" void kernel_launch(void* const* d_in, const int* in_sizes, int n_in,
                              void* d_out, int out_size, void* d_ws, size_t ws_size,
                              hipStream_t stream) {
  const float* Q    = (const float*)d_in[0];
  const float* K    = (const float*)d_in[1];
  const float* V    = (const float*)d_in[2];
  const float* mask = (const float*)d_in[3];
  const float* proj = (const float*)d_in[4];
  float* out = (float*)d_out;
  float* ws = (float*)d_ws;

  unsigned short* wBx = (unsigned short*)(ws + OFF_BX);
  unsigned short* wCs = (unsigned short*)(ws + OFF_CS);
  float* wKsump = ws + OFF_KSUMP;
  float* wKsumG = ws + OFF_KSUMG;
  float* wVsp   = ws + OFF_VSP;
  float* wCtxp  = ws + OFF_CTXP;

  kPrep<<<8, 256, 0, stream>>>(proj, wBx);
  kCtx<<<dim3(16, NHEADS), 512, 0, stream>>>(K, V, mask, wBx, wCtxp, wKsump, wKsumG, wVsp);
  kRedCtx<<<NHEADS, 256, 0, stream>>>(wCtxp, wKsump, wVsp, wCs, wKsumG);
  kOut<<<dim3(8, NHEADS), 512, 0, stream>>>(Q, wBx, wCs, wKsumG, out);
}

// Round 12
// 127.999 us; speedup vs baseline: 2.3782x; 1.0419x over previous
//
#include <hip/hip_runtime.h>

// Performer (FAVOR+) self-attention. B=4 H=8 N=8192 D=64 M=256.
// Round 22 = r19/r21 + kOut cross-block overlap (the kCtx r12 medicine,
// applied WITHOUT a register cap):
//  - kOut: 256-thread blocks (4 waves), 64-row chunks, Ff [64][260] 33.3 KB,
//    LDS 65.8 KB -> 2 blocks/CU; launch_bounds(256,2) = 256-reg cap (est
//    peak ~171 live, no spill possible). p1 per-wave math identical (full
//    accC[16] per 16 rows -> exact rowmax). p2: wave w owns d-col w*16 for
//    all 64 rows (cb[8] = dt=w frags). Grid 1024 blocks.
//  - Gain mechanism: two independent blocks per CU interleave their serial
//    phases across barriers (same as kCtx r12's 150->77 win).
// kCtx/kRedCtx/kPrep identical to r21 (best measured 133.4 us).
// kPrep -> kCtx -> kRedCtx -> kOut

typedef __attribute__((ext_vector_type(8))) short short8;
typedef __attribute__((ext_vector_type(8))) _Float16 half8;
typedef __attribute__((ext_vector_type(4))) float f32x4;

namespace {
constexpr int BN = 8192, DD = 64, MM = 256, NHEADS = 32;
constexpr float CNORM = 0.35355339059327373f;   // D^-0.25
constexpr float LOG2E = 1.4426950408889634f;
constexpr float DGC   = 0.34657359027997264f;   // 0.5/LOG2E
constexpr float FEPS  = 1e-4f;
constexpr float INV2048 = 4.8828125e-4f;
constexpr int FFS = 260;                        // kOut Ff stride (ushorts)

// workspace layout in floats (total 4,555,008 f = 18.22 MB)
constexpr size_t OFF_BX    = 0;         // 16384 ushort = 8192 f
constexpr size_t OFF_CS    = 8192;      // 32*16384 ushort -> ends 270336
constexpr size_t OFF_KSUMP = 270336;    // 32*16*128 = 65536 -> 335872
constexpr size_t OFF_KSUMG = 335872;    // 32*256 = 8192 -> 344064 (mx packed @ +240..255/bh)
constexpr size_t OFF_VSP   = 344320;    // 32*8*64 = 16384 -> 360704
constexpr size_t OFF_CTXP  = 360704;    // 32*16*8192 = 4194304 -> 4555008
}

__device__ __forceinline__ unsigned short f2bf(float f) {
  unsigned u = __float_as_uint(f);
  u += 0x7fffu + ((u >> 16) & 1u);
  return (unsigned short)(u >> 16);
}
__device__ __forceinline__ float bf2f(unsigned short h) {
  return __uint_as_float(((unsigned)h) << 16);
}
__device__ __forceinline__ unsigned pk2(unsigned short a, unsigned short b) {
  return (unsigned)a | ((unsigned)b << 16);
}
__device__ __forceinline__ unsigned short f2h(float f) {
  _Float16 h = (_Float16)f;
  return __builtin_bit_cast(unsigned short, h);
}
__device__ __forceinline__ float exp2hw(float x) {
  float r;
  asm("v_exp_f32 %0, %1" : "=v"(r) : "v"(x));
  return r;
}
__device__ __forceinline__ unsigned cvtpk(float lo, float hi) {
  unsigned r;
  asm("v_cvt_pk_bf16_f32 %0, %1, %2" : "=v"(r) : "v"(lo), "v"(hi));
  return r;
}

// XCD swizzle: linear id -> (bh, tile); each XCD owns 4 consecutive heads.
template <int T>
__device__ __forceinline__ void xcd_map(int& bh, int& tile) {
  int id = blockIdx.y * T + blockIdx.x;
  int xcd = id & 7, s = id >> 3;
  bh = xcd * 4 + s / T;
  tile = s % T;
}

// ---------------- kPrep: proj -> single-f16 frag stream (32 KB) ----------------
// BxG[mt 16][kb 2][lane 64][8 f16]; kb = K-half (d 0-31 / 32-63).
__global__ void kPrep(const float* __restrict__ proj, unsigned short* __restrict__ BxG) {
  int s = blockIdx.x * 256 + threadIdx.x;   // 0..2047
  int l = s & 63, kb = (s >> 6) & 1, mt = s >> 7;
  int n = mt * 16 + (l & 15);
  int k0 = kb * 32 + (l >> 4) * 8;
  unsigned short o[8];
#pragma unroll
  for (int j = 0; j < 8; ++j) o[j] = f2h(proj[n * 64 + k0 + j]);
  *(uint4*)(BxG + (size_t)s * 8) =
      make_uint4(pk2(o[0], o[1]), pk2(o[2], o[3]), pk2(o[4], o[5]), pk2(o[6], o[7]));
}

// ---------------- kCtx: unscaled k-feature pipeline -> ctx/ksum partials + max ----------------
// Block = (bh, tile, mh): 1024 rows (8 chunks x 128), m-half mh*128..+128.
__global__ void __launch_bounds__(512, 4)
kCtx(const float* __restrict__ Kin, const float* __restrict__ Vin,
     const float* __restrict__ mask, const unsigned short* __restrict__ BxG,
     float* __restrict__ ctxp, float* __restrict__ ksump,
     float* __restrict__ mxg, float* __restrict__ vsp) {
  __shared__ __align__(16) unsigned short BxH[8192];      // 16 KB (this m-half of proj)
  __shared__ __align__(16) unsigned short Fs[128 * 140];  // 35 KB features [m][n], stride 140
  __shared__ __align__(16) unsigned short VF[16 * 64 * 8];// 16 KB [ks4][dt4][lane64][8] bf16
  __shared__ float wmax[8];
  __shared__ float ksred[1024];
  __shared__ float vred[512];
  const int tid = threadIdx.x;
  int bh, tl16;
  xcd_map<16>(bh, tl16);
  const int tile = tl16 >> 1, mh = tl16 & 1;
  const int b = bh >> 3;
  const float* Kh = Kin + (size_t)bh * BN * DD;
  const float* Vh = Vin + (size_t)bh * BN * DD;
  const float* mrow = mask + (size_t)b * BN;
#pragma unroll
  for (int i = 0; i < 2; ++i)
    ((uint4*)BxH)[tid + i * 512] = ((const uint4*)BxG)[mh * 1024 + tid + i * 512];
  const int w = tid >> 6, l = tid & 63, lm = l & 15, kl = l >> 4;
  const int lmv = tid & 15, klnv = (tid >> 4) & 3, dtv = (tid >> 6) & 3, ksv0 = tid >> 8;

  f32x4 cacc[4];
#pragma unroll
  for (int dt = 0; dt < 4; ++dt) cacc[dt] = f32x4{0.f, 0.f, 0.f, 0.f};
  float kspart[8] = {0.f, 0.f, 0.f, 0.f, 0.f, 0.f, 0.f, 0.f};
  float wm = -3e38f, vsum = 0.f;

  const int rbase = tile * 1024;
  float4 kv0, kv1, kv2, kv3;
  float mskK;
  {
    const float* rp = Kh + (size_t)(rbase + w * 16 + lm) * 64 + kl * 8;
    kv0 = *(const float4*)rp;        kv1 = *(const float4*)(rp + 4);
    kv2 = *(const float4*)(rp + 32); kv3 = *(const float4*)(rp + 36);
    mskK = mrow[rbase + w * 16 + lm];
  }
  __syncthreads();   // BxH ready

  for (int ch = 0; ch < 8; ++ch) {
    const int r0 = rbase + ch * 128;
    // ---- convert own K row regs -> hi/lo f16 A-frags (LOG2E folded) + diag ----
    half8 ah0, ah1, al0, al1;
    float diagv;
    {
      float scale = CNORM * LOG2E * mskK;
      float x[16] = {kv0.x, kv0.y, kv0.z, kv0.w, kv1.x, kv1.y, kv1.z, kv1.w,
                     kv2.x, kv2.y, kv2.z, kv2.w, kv3.x, kv3.y, kv3.z, kv3.w};
      float sq = 0.f;
#pragma unroll
      for (int e = 0; e < 16; ++e) {
        float y = x[e] * scale;
        _Float16 h = (_Float16)y;
        _Float16 lo = (_Float16)((y - (float)h) * 2048.0f);
        if (e < 8) { ah0[e] = h; al0[e] = lo; } else { ah1[e - 8] = h; al1[e - 8] = lo; }
        sq = fmaf(y, y, sq);
      }
      sq += __shfl_xor(sq, 16);
      sq += __shfl_xor(sq, 32);
      diagv = DGC * sq;   // = LOG2E * 0.5 * |x*CNORM|^2
    }
    // ---- prefetch next chunk's K rows ----
    {
      const int nr = rbase + ((ch + 1) & 7) * 128 + w * 16 + lm;
      const float* rp = Kh + (size_t)nr * 64 + kl * 8;
      kv0 = *(const float4*)rp;        kv1 = *(const float4*)(rp + 4);
      kv2 = *(const float4*)(rp + 32); kv3 = *(const float4*)(rp + 36);
      mskK = mrow[nr];
    }
    // ---- issue V loads (consumed after p1) ----
    float vv[16];
#pragma unroll
    for (int h = 0; h < 2; ++h) {
      int nb = (ksv0 * 2 + h) * 32 + klnv * 8;
#pragma unroll
      for (int j = 0; j < 8; ++j)
        vv[h * 8 + j] = Vh[(size_t)(r0 + nb + j) * 64 + dtv * 16 + lmv];
    }
    // ---- p1 fused with features: per j, 4 MFMAs -> exp2 -> bf16 -> Fs ----
    float dgv[4];
#pragma unroll
    for (int r = 0; r < 4; ++r)
      dgv[r] = __shfl(diagv, (l & 48) + kl * 4 + r);
#pragma unroll
    for (int j = 0; j < 8; ++j) {
      half8 b0 = *(const half8*)&BxH[((j * 2 + 0) * 64 + l) * 8];
      half8 b1 = *(const half8*)&BxH[((j * 2 + 1) * 64 + l) * 8];
      f32x4 a0 = {0.f, 0.f, 0.f, 0.f}, a1 = {0.f, 0.f, 0.f, 0.f};
      a0 = __builtin_amdgcn_mfma_f32_16x16x32_f16(ah0, b0, a0, 0, 0, 0);
      a0 = __builtin_amdgcn_mfma_f32_16x16x32_f16(ah1, b1, a0, 0, 0, 0);
      a1 = __builtin_amdgcn_mfma_f32_16x16x32_f16(al0, b0, a1, 0, 0, 0);
      a1 = __builtin_amdgcn_mfma_f32_16x16x32_f16(al1, b1, a1, 0, 0, 0);
      float x0 = fmaf(a1[0], INV2048, a0[0]);
      float x1 = fmaf(a1[1], INV2048, a0[1]);
      float x2 = fmaf(a1[2], INV2048, a0[2]);
      float x3 = fmaf(a1[3], INV2048, a0[3]);
      wm = fmaxf(wm, fmaxf(fmaxf(x0, x1), fmaxf(x2, x3)));
      float f0 = exp2hw(x0 - dgv[0]);
      float f1 = exp2hw(x1 - dgv[1]);
      float f2 = exp2hw(x2 - dgv[2]);
      float f3 = exp2hw(x3 - dgv[3]);
      kspart[j] += f0 + f1 + f2 + f3;
      *(uint2*)&Fs[(j * 16 + lm) * 140 + w * 16 + kl * 4] =
          make_uint2(cvtpk(f0, f1), cvtpk(f2, f3));
    }
    // ---- V -> VF (bf16 frag-linear) + masked V row-sum ----
#pragma unroll
    for (int h = 0; h < 2; ++h) {
      int ks = ksv0 * 2 + h;
      int nb = ks * 32 + klnv * 8;
      float4 m0 = *(const float4*)&mrow[r0 + nb];
      float4 m1 = *(const float4*)&mrow[r0 + nb + 4];
      float mk[8] = {m0.x, m0.y, m0.z, m0.w, m1.x, m1.y, m1.z, m1.w};
      float vm[8];
#pragma unroll
      for (int j = 0; j < 8; ++j) {
        vm[j] = vv[h * 8 + j] * mk[j];
        vsum += vm[j];
      }
      *(uint4*)&VF[((ks * 4 + dtv) * 64 + klnv * 16 + lmv) * 8] =
          make_uint4(cvtpk(vm[0], vm[1]), cvtpk(vm[2], vm[3]),
                     cvtpk(vm[4], vm[5]), cvtpk(vm[6], vm[7]));
    }
    __syncthreads();   // barrier 1: Fs + VF ready
    // ---- p2: ctx[m][d] += k'^T V; wave w owns m-rows w*16..+16 ----
#pragma unroll
    for (int ks = 0; ks < 4; ++ks) {
      union { short8 v; uint2 u[2]; } af;
      const int ab = (w * 16 + lm) * 140 + ks * 32 + kl * 8;
      af.u[0] = *(const uint2*)&Fs[ab];
      af.u[1] = *(const uint2*)&Fs[ab + 4];
#pragma unroll
      for (int dt = 0; dt < 4; ++dt) {
        short8 vb = *(const short8*)&VF[((ks * 4 + dt) * 64 + l) * 8];
        cacc[dt] = __builtin_amdgcn_mfma_f32_16x16x32_bf16(af.v, vb, cacc[dt], 0, 0, 0);
      }
    }
    __syncthreads();   // barrier 2: p2 reads done before next chunk's writes
  }
  // ---- epilogue ----
#pragma unroll
  for (int j = 0; j < 8; ++j) {
    kspart[j] += __shfl_xor(kspart[j], 16);
    kspart[j] += __shfl_xor(kspart[j], 32);
  }
  if (l < 16) {
#pragma unroll
    for (int j = 0; j < 8; ++j) ksred[(j * 16 + l) * 8 + w] = kspart[j];
  }
  {
    wm = fmaxf(wm, __shfl_xor(wm, 1));  wm = fmaxf(wm, __shfl_xor(wm, 2));
    wm = fmaxf(wm, __shfl_xor(wm, 4));  wm = fmaxf(wm, __shfl_xor(wm, 8));
    wm = fmaxf(wm, __shfl_xor(wm, 16)); wm = fmaxf(wm, __shfl_xor(wm, 32));
    if (l == 0) wmax[w] = wm;
  }
  vred[tid] = vsum;
  __syncthreads();
  if (tid < 128) {
    float s = 0.f;
#pragma unroll
    for (int k = 0; k < 8; ++k) s += ksred[tid * 8 + k];
    ksump[(size_t)(bh * 16 + tl16) * 128 + tid] = s;
  }
  if (mh == 0 && tid < 64) {
    float vs = 0.f;
#pragma unroll
    for (int k = 0; k < 8; ++k)
      vs += vred[(k >> 2) * 256 + (tid >> 4) * 64 + (k & 3) * 16 + (tid & 15)];
    vsp[(size_t)(bh * 8 + tile) * 64 + tid] = vs;
  }
  if (tid == 0) {
    float bm = wmax[0];
#pragma unroll
    for (int i = 1; i < 8; ++i) bm = fmaxf(bm, wmax[i]);
    mxg[bh * 256 + 240 + tl16] = bm;   // log2-units max, packed into ksumG tail
  }
  float* cp = ctxp + (size_t)(bh * 16 + tl16) * 8192;
#pragma unroll
  for (int dt = 0; dt < 4; ++dt)
#pragma unroll
    for (int r = 0; r < 4; ++r)
      cp[(w * 16 + kl * 4 + r) * 64 + dt * 16 + lm] = cacc[dt][r];
}

// ---------------- kRedCtx: sum partials, scale exp2(-MX), eps terms ----------------
__global__ void kRedCtx(const float* __restrict__ ctxp, const float* __restrict__ ksump,
                        const float* __restrict__ vsp, unsigned short* __restrict__ CsG,
                        float* __restrict__ ksumG) {
  __shared__ __align__(16) float ctxL[16384];
  __shared__ float vsL[64];
  const int bh = blockIdx.x, t = threadIdx.x;   // 256 threads
  float MX = -3e38f;
#pragma unroll
  for (int i = 0; i < 16; ++i) MX = fmaxf(MX, ksumG[bh * 256 + 240 + i]);  // packed maxes
  const float fsc = exp2hw(-MX);
  __syncthreads();   // all threads read packed maxes before any ksumG writes
#pragma unroll
  for (int i = 0; i < 16; ++i) {
    int idx4 = t + i * 256;                 // float4 index; m = idx4>>4
    int mhi = (idx4 >> 11) & 1;             // m-half
    int loc = idx4 & 2047;
    float4 s = make_float4(0.f, 0.f, 0.f, 0.f);
#pragma unroll
    for (int tl = 0; tl < 8; ++tl) {
      float4 a = ((const float4*)(ctxp + (size_t)(bh * 16 + tl * 2 + mhi) * 8192))[loc];
      s.x += a.x; s.y += a.y; s.z += a.z; s.w += a.w;
    }
    s.x *= fsc; s.y *= fsc; s.z *= fsc; s.w *= fsc;
    ((float4*)ctxL)[idx4] = s;
  }
  {
    int mhi = t >> 7, loc = t & 127;
    float ks = 0.f;
#pragma unroll
    for (int tl = 0; tl < 8; ++tl)
      ks += ksump[(size_t)(bh * 16 + tl * 2 + mhi) * 128 + loc];
    ksumG[bh * 256 + t] = fsc * ks + FEPS * (float)BN;
  }
  if (t < 64) {
    float vs = 0.f;
#pragma unroll
    for (int tl = 0; tl < 8; ++tl) vs += vsp[(size_t)(bh * 8 + tl) * 64 + t];
    vsL[t] = vs;
  }
  __syncthreads();
#pragma unroll
  for (int i = 0; i < 8; ++i) {
    int slot = t + i * 256;   // [dt 4][s 8][lane 64]
    int l = slot & 63, s = (slot >> 6) & 7, dt = slot >> 9;
    int d = dt * 16 + (l & 15);
    int mb = s * 32 + (l >> 4) * 8;
    float ve = FEPS * vsL[d];
    unsigned short o[8];
#pragma unroll
    for (int j = 0; j < 8; ++j) o[j] = f2bf(ctxL[(mb + j) * 64 + d] + ve);
    *(uint4*)(CsG + (size_t)bh * 16384 + (size_t)slot * 8) =
        make_uint4(pk2(o[0], o[1]), pk2(o[2], o[3]), pk2(o[4], o[5]), pk2(o[6], o[7]));
  }
}

// ---------------- kOut: 256-thr, 64-row chunks, 2 blocks/CU ----------------
// 1024 blocks (32 tiles x 32 bh), 256 thr (4 waves), 4 chunks x 64 rows.
// p1: wave w owns rows w*16..+16 (full 256-m accC[16], exact rowmax).
// p2: wave w owns d-col w*16..+16 for all 64 rows (cb[8] = dt=w frags).
// LDS 65.8 KB -> 2 blocks/CU; launch_bounds(256,2) -> 256-reg cap (no spill).
__global__ void __launch_bounds__(256, 2)
kOut(const float* __restrict__ Qin, const unsigned short* __restrict__ BxG,
     const unsigned short* __restrict__ CsG, const float* __restrict__ ksumG,
     float* __restrict__ outp) {
  __shared__ __align__(16) unsigned short BxH[16384];   // 32 KB
  __shared__ __align__(16) unsigned short Ff[64 * FFS]; // 33.3 KB q-features bf16
  __shared__ float den[64];                             // 1/denominator per row
  const int tid = threadIdx.x;
  int bh, tile;
  xcd_map<32>(bh, tile);
  const float* Qh = Qin + (size_t)bh * BN * DD;
  const unsigned short* CsB = CsG + (size_t)bh * 16384;
  const int w = tid >> 6, l = tid & 63, lm = l & 15, kl = l >> 4;
#pragma unroll
  for (int i = 0; i < 16; ++i)
    ((uint4*)BxH)[tid + i * 256] = ((const uint4*)BxG)[tid + i * 256];
  short8 cb[8];   // ctx frags for d-col w*16..+16
#pragma unroll
  for (int s = 0; s < 8; ++s)
    cb[s] = *(const short8*)(CsB + (size_t)(((w * 8 + s) * 64 + l) * 8));
  float kss[16];
#pragma unroll
  for (int j = 0; j < 16; ++j) kss[j] = ksumG[bh * 256 + j * 16 + lm];
  // peel: q regs for chunk 0
  float4 qv0, qv1, qv2, qv3;
  {
    const float* rp = Qh + (size_t)(tile * 256 + w * 16 + lm) * 64 + kl * 8;
    qv0 = *(const float4*)rp;        qv1 = *(const float4*)(rp + 4);
    qv2 = *(const float4*)(rp + 32); qv3 = *(const float4*)(rp + 36);
  }
  __syncthreads();   // BxH ready

  for (int ch = 0; ch < 4; ++ch) {
    const int r0 = tile * 256 + ch * 64;
    // ---- convert own q row regs -> hi/lo f16 A-frags + diag ----
    half8 ah0, ah1, al0, al1;
    float sq = 0.f;
    {
      const float scale = CNORM * LOG2E;
      float x[16] = {qv0.x, qv0.y, qv0.z, qv0.w, qv1.x, qv1.y, qv1.z, qv1.w,
                     qv2.x, qv2.y, qv2.z, qv2.w, qv3.x, qv3.y, qv3.z, qv3.w};
#pragma unroll
      for (int e = 0; e < 16; ++e) {
        float y = x[e] * scale;
        _Float16 h = (_Float16)y;
        _Float16 lo = (_Float16)((y - (float)h) * 2048.0f);
        if (e < 8) { ah0[e] = h; al0[e] = lo; } else { ah1[e - 8] = h; al1[e - 8] = lo; }
        sq = fmaf(y, y, sq);
      }
      sq += __shfl_xor(sq, 16);
      sq += __shfl_xor(sq, 32);
    }
    const float diagv = DGC * sq;   // log2 units
    // ---- prefetch next chunk's q rows ----
    {
      const int nr = tile * 256 + ((ch + 1) & 3) * 64 + w * 16 + lm;
      const float* rp = Qh + (size_t)nr * 64 + kl * 8;
      qv0 = *(const float4*)rp;        qv1 = *(const float4*)(rp + 4);
      qv2 = *(const float4*)(rp + 32); qv3 = *(const float4*)(rp + 36);
    }
    // ---- p1: full 256-m xd for own 16 rows ----
    f32x4 accC[16];
#pragma unroll
    for (int j = 0; j < 16; ++j) {
      half8 b0 = *(const half8*)&BxH[((j * 2 + 0) * 64 + l) * 8];
      half8 b1 = *(const half8*)&BxH[((j * 2 + 1) * 64 + l) * 8];
      f32x4 acc0 = {0.f, 0.f, 0.f, 0.f}, acc1 = {0.f, 0.f, 0.f, 0.f};
      acc0 = __builtin_amdgcn_mfma_f32_16x16x32_f16(ah0, b0, acc0, 0, 0, 0);
      acc0 = __builtin_amdgcn_mfma_f32_16x16x32_f16(ah1, b1, acc0, 0, 0, 0);
      acc1 = __builtin_amdgcn_mfma_f32_16x16x32_f16(al0, b0, acc1, 0, 0, 0);
      acc1 = __builtin_amdgcn_mfma_f32_16x16x32_f16(al1, b1, acc1, 0, 0, 0);
#pragma unroll
      for (int r = 0; r < 4; ++r) accC[j][r] = fmaf(acc1[r], INV2048, acc0[r]);
    }
    float mrow[4];
#pragma unroll
    for (int r = 0; r < 4; ++r) {
      float m0 = accC[0][r];
#pragma unroll
      for (int j = 1; j < 16; ++j) m0 = fmaxf(m0, accC[j][r]);
      m0 = fmaxf(m0, __shfl_xor(m0, 1));
      m0 = fmaxf(m0, __shfl_xor(m0, 2));
      m0 = fmaxf(m0, __shfl_xor(m0, 4));
      m0 = fmaxf(m0, __shfl_xor(m0, 8));
      mrow[r] = m0;
    }
    float dgv[4], dnn[4] = {0.f, 0.f, 0.f, 0.f};
#pragma unroll
    for (int r = 0; r < 4; ++r)
      dgv[r] = __shfl(diagv, (l & 48) + kl * 4 + r) + mrow[r];
#pragma unroll
    for (int j = 0; j < 16; ++j) {
#pragma unroll
      for (int r = 0; r < 4; ++r) {
        float q = exp2hw(accC[j][r] - dgv[r]) + FEPS;
        unsigned short qh = f2bf(q);
        Ff[(w * 16 + kl * 4 + r) * FFS + j * 16 + lm] = qh;
        dnn[r] += bf2f(qh) * kss[j];
      }
    }
#pragma unroll
    for (int r = 0; r < 4; ++r) {
      dnn[r] += __shfl_xor(dnn[r], 1); dnn[r] += __shfl_xor(dnn[r], 2);
      dnn[r] += __shfl_xor(dnn[r], 4); dnn[r] += __shfl_xor(dnn[r], 8);
    }
    if (lm == 0) {
#pragma unroll
      for (int r = 0; r < 4; ++r) den[w * 16 + kl * 4 + r] = 1.0f / dnn[r];
    }
    __syncthreads();   // features + den ready for all waves
    // ---- p2: wave w -> d-col w*16..+16, all 64 rows ----
    f32x4 oacc[4];
#pragma unroll
    for (int fr = 0; fr < 4; ++fr) oacc[fr] = f32x4{0.f, 0.f, 0.f, 0.f};
#pragma unroll
    for (int s = 0; s < 8; ++s) {
#pragma unroll
      for (int fr = 0; fr < 4; ++fr) {
        short8 af = *(const short8*)&Ff[(fr * 16 + lm) * FFS + s * 32 + kl * 8];
        oacc[fr] = __builtin_amdgcn_mfma_f32_16x16x32_bf16(af, cb[s], oacc[fr], 0, 0, 0);
      }
    }
#pragma unroll
    for (int fr = 0; fr < 4; ++fr) {
#pragma unroll
      for (int r = 0; r < 4; ++r) {
        int n = fr * 16 + kl * 4 + r;
        outp[((size_t)bh * BN + r0 + n) * 64 + w * 16 + lm] = oacc[fr][r] * den[n];
      }
    }
    __syncthreads();   // p2 reads done before next chunk overwrites Ff
  }
}

extern "C" void kernel_launch(void* const* d_in, const int* in_sizes, int n_in,
                              void* d_out, int out_size, void* d_ws, size_t ws_size,
                              hipStream_t stream) {
  const float* Q    = (const float*)d_in[0];
  const float* K    = (const float*)d_in[1];
  const float* V    = (const float*)d_in[2];
  const float* mask = (const float*)d_in[3];
  const float* proj = (const float*)d_in[4];
  float* out = (float*)d_out;
  float* ws = (float*)d_ws;

  unsigned short* wBx = (unsigned short*)(ws + OFF_BX);
  unsigned short* wCs = (unsigned short*)(ws + OFF_CS);
  float* wKsump = ws + OFF_KSUMP;
  float* wKsumG = ws + OFF_KSUMG;
  float* wVsp   = ws + OFF_VSP;
  float* wCtxp  = ws + OFF_CTXP;

  kPrep<<<8, 256, 0, stream>>>(proj, wBx);
  kCtx<<<dim3(16, NHEADS), 512, 0, stream>>>(K, V, mask, wBx, wCtxp, wKsump, wKsumG, wVsp);
  kRedCtx<<<NHEADS, 256, 0, stream>>>(wCtxp, wKsump, wVsp, wCs, wKsumG);
  kOut<<<dim3(32, NHEADS), 256, 0, stream>>>(Q, wBx, wCs, wKsumG, out);
}